// Round 17
// baseline (281.695 us; speedup 1.0000x reference)
//
#include <hip/hip_runtime.h>
#include <hip/hip_fp16.h>
#include <cmath>

#define HEADS 4
#define HID 32
#define IN_DIM 128
#define OUT_DIM 64
#define D1 (HEADS*HID)   /* 128 */
#define NEG_SLOPE 0.2f
#define BN_EPS 1e-5f
#define BSHIFT 6         /* 64 nodes per dst-bucket */
#define NBLK 128         /* blocks for hist/scatter passes */

__device__ __forceinline__ float2 h2f2(unsigned u) {
  return __half22float2(*reinterpret_cast<const __half2*>(&u));
}

// gather bodies (straight-line; rely on w=0/sj=0 masking for invalid lanes)
#define GATH1(J2) { int k_ = (J2)*2 + h; \
  float wv_ = __shfl(w, lbase + k_); int sv_ = __shfl(sj, k_); \
  uint2 hv_ = hp4[(size_t)sv_*32 + g]; \
  float2 p0_ = h2f2(hv_.x), p1_ = h2f2(hv_.y); \
  a0 = fmaf(p0_.x, wv_, a0); a1 = fmaf(p0_.y, wv_, a1); \
  a2 = fmaf(p1_.x, wv_, a2); a3 = fmaf(p1_.y, wv_, a3); }

#define GATH2(J2) { int k_ = (J2)*4 + q; \
  float wv_ = __shfl(w, k_); int sv_ = __shfl(sj, k_); \
  uint2 hv_ = hp4[(size_t)sv_*16 + g]; \
  float2 p0_ = h2f2(hv_.x), p1_ = h2f2(hv_.y); \
  a0 = fmaf(p0_.x, wv_, a0); a1 = fmaf(p0_.y, wv_, a1); \
  a2 = fmaf(p1_.x, wv_, a2); a3 = fmaf(p1_.y, wv_, a3); }

// ================= CSR build: blocked counting sort =================

__global__ void hist_pass(const int* __restrict__ ei, int E, int n, int chunk,
                          unsigned* __restrict__ histg, unsigned* __restrict__ deg)
{
  __shared__ unsigned h[1024];
  int blk = blockIdx.x, tid = threadIdx.x;
  int nb = (n + 63) >> BSHIFT;
  for (int i = tid; i < nb; i += 256) h[i] = 0u;
  __syncthreads();
  int beg = blk*chunk, end_ = min(beg + chunk, E + n);
  for (int t = beg + tid; t < end_; t += 256) {
    int d_;
    if (t < E) { d_ = ei[E + t]; atomicAdd(&deg[d_], 1u); }
    else d_ = t - E;
    atomicAdd(&h[d_ >> BSHIFT], 1u);
  }
  __syncthreads();
  for (int i = tid; i < nb; i += 256) histg[(size_t)i*NBLK + blk] = h[i];
}

__global__ void gsum(const unsigned* __restrict__ in, unsigned* __restrict__ part, int total)
{
  __shared__ unsigned red[256];
  int tid = threadIdx.x;
  int i = blockIdx.x*256 + tid;
  red[tid] = (i < total) ? in[i] : 0u;
  __syncthreads();
  for (int o = 128; o >= 1; o >>= 1) {
    if (tid < o) red[tid] += red[tid + o];
    __syncthreads();
  }
  if (tid == 0) part[blockIdx.x] = red[0];
}

__global__ void gscan_part(unsigned* __restrict__ part, int ntiles)
{
  __shared__ unsigned sh[256];
  int tid = threadIdx.x;
  unsigned carry = 0;
  for (int base = 0; base < ntiles; base += 256) {
    int i = base + tid;
    unsigned v = (i < ntiles) ? part[i] : 0u;
    sh[tid] = v;
    __syncthreads();
    for (int o = 1; o < 256; o <<= 1) {
      unsigned t = (tid >= o) ? sh[tid - o] : 0u;
      __syncthreads();
      sh[tid] += t;
      __syncthreads();
    }
    if (i < ntiles) part[i] = carry + sh[tid] - v;
    unsigned tot = sh[255];
    __syncthreads();
    carry += tot;
  }
}

__global__ void gscan_write(const unsigned* __restrict__ in, const unsigned* __restrict__ part,
                            unsigned* __restrict__ out, int total)
{
  __shared__ unsigned sh[256];
  int tid = threadIdx.x;
  int i = blockIdx.x*256 + tid;
  unsigned v = (i < total) ? in[i] : 0u;
  sh[tid] = v;
  __syncthreads();
  for (int o = 1; o < 256; o <<= 1) {
    unsigned t = (tid >= o) ? sh[tid - o] : 0u;
    __syncthreads();
    sh[tid] += t;
    __syncthreads();
  }
  if (i < total) out[i] = part[blockIdx.x] + sh[tid] - v;
}

__global__ void scatter_pass(const int* __restrict__ ei, int E, int n, int chunk,
                             const unsigned* __restrict__ scanned, int2* __restrict__ pairs)
{
  __shared__ unsigned basel[1024];
  __shared__ unsigned lcur[1024];
  int blk = blockIdx.x, tid = threadIdx.x;
  int nb = (n + 63) >> BSHIFT;
  for (int i = tid; i < nb; i += 256) {
    basel[i] = scanned[(size_t)i*NBLK + blk];
    lcur[i] = 0u;
  }
  __syncthreads();
  int beg = blk*chunk, end_ = min(beg + chunk, E + n);
  for (int t = beg + tid; t < end_; t += 256) {
    int s_, d_;
    if (t < E) { s_ = ei[t]; d_ = ei[E + t]; } else { s_ = d_ = t - E; }
    int b = d_ >> BSHIFT;
    unsigned r = atomicAdd(&lcur[b], 1u);
    pairs[basel[b] + r] = make_int2(s_, d_);
  }
}

__global__ void bucket_fill(const int2* __restrict__ pairs, const unsigned* __restrict__ scanned,
                            const unsigned* __restrict__ offs, int* __restrict__ csr,
                            int nb, int total)
{
  __shared__ unsigned curs[64];
  int b = blockIdx.x, tid = threadIdx.x;
  if (tid < 64) curs[tid] = 0u;
  __syncthreads();
  unsigned pb = scanned[(size_t)b*NBLK];
  unsigned pe = (b + 1 < nb) ? scanned[(size_t)(b+1)*NBLK] : (unsigned)total;
  for (unsigned i = pb + tid; i < pe; i += blockDim.x) {
    int2 pr = pairs[i];
    unsigned rank = atomicAdd(&curs[pr.y & 63], 1u);
    csr[offs[pr.y] + rank] = pr.x;
  }
}

__global__ void tile_sum(const unsigned* __restrict__ deg, unsigned* __restrict__ part, int n)
{
  __shared__ unsigned red[256];
  int tid = threadIdx.x;
  int i = blockIdx.x*256 + tid;
  red[tid] = (i < n) ? deg[i] + 1u : 0u;
  __syncthreads();
  for (int o = 128; o >= 1; o >>= 1) {
    if (tid < o) red[tid] += red[tid + o];
    __syncthreads();
  }
  if (tid == 0) part[blockIdx.x] = red[0];
}

__global__ void part_scan(unsigned* __restrict__ part, unsigned* __restrict__ offs_n, int ntiles)
{
  __shared__ unsigned sh[256];
  int tid = threadIdx.x;
  unsigned carry = 0;
  for (int base = 0; base < ntiles; base += 256) {
    int i = base + tid;
    unsigned v = (i < ntiles) ? part[i] : 0u;
    sh[tid] = v;
    __syncthreads();
    for (int o = 1; o < 256; o <<= 1) {
      unsigned t = (tid >= o) ? sh[tid - o] : 0u;
      __syncthreads();
      sh[tid] += t;
      __syncthreads();
    }
    unsigned incl = sh[tid];
    if (i < ntiles) part[i] = carry + incl - v;
    unsigned tot = sh[255];
    __syncthreads();
    carry += tot;
  }
  if (tid == 0) offs_n[0] = carry;
}

__global__ void tile_scan_write(const unsigned* __restrict__ deg, const unsigned* __restrict__ part,
                                unsigned* __restrict__ offs, int n)
{
  __shared__ unsigned sh[256];
  int tid = threadIdx.x;
  int i = blockIdx.x*256 + tid;
  unsigned v = (i < n) ? deg[i] + 1u : 0u;
  sh[tid] = v;
  __syncthreads();
  for (int o = 1; o < 256; o <<= 1) {
    unsigned t = (tid >= o) ? sh[tid - o] : 0u;
    __syncthreads();
    sh[tid] += t;
    __syncthreads();
  }
  if (i < n) offs[i] = part[blockIdx.x] + sh[tid] - v;
}

__global__ void prep_wa(const float* __restrict__ W2, const float* __restrict__ a2s,
                        const float* __restrict__ a2d,
                        float* __restrict__ wa_s, float* __restrict__ wa_d)
{
  int k = threadIdx.x;
  float s = 0.f, d = 0.f;
  for (int j = 0; j < OUT_DIM; ++j) {
    float w = W2[k*OUT_DIM + j];
    s = fmaf(w, a2s[j], s);
    d = fmaf(w, a2d[j], d);
  }
  wa_s[k] = s; wa_d[k] = d;
}

// ================= dense GEMMs: register-blocked tiles =================
// K-loops carry a global W load per iteration; WITHOUT unrolling the compiler
// keeps one load in flight (VGPR=32, 49us). unroll 8 => 8 loads in flight.

__global__ void gemm1(const float* __restrict__ x, const float* __restrict__ W,
                      const float* __restrict__ a_s, const float* __restrict__ a_d,
                      __half2* __restrict__ h, float* __restrict__ asn,
                      float* __restrict__ adn, int n)
{
  __shared__ float xt[IN_DIM][33];
  int tid = threadIdx.x;
  int base = blockIdx.x * 32;
  for (int idx = tid; idx < 32*IN_DIM; idx += 256) {
    int node = idx >> 7, k = idx & 127;
    int gn = base + node;
    xt[k][node] = (gn < n) ? x[(size_t)gn*IN_DIM + k] : 0.f;
  }
  __syncthreads();
  int ng = tid & 7, cg = tid >> 3;
  int n0 = ng * 4, c0 = cg * 4;
  float acc[4][4];
  #pragma unroll
  for (int i = 0; i < 4; ++i) { acc[i][0]=0.f; acc[i][1]=0.f; acc[i][2]=0.f; acc[i][3]=0.f; }
  #pragma unroll 8
  for (int k = 0; k < IN_DIM; ++k) {
    float4 w = *(const float4*)(W + k*D1 + c0);
    float2 z01 = *(const float2*)&xt[k][n0];
    float2 z23 = *(const float2*)&xt[k][n0+2];
    float zz0=z01.x, zz1=z01.y, zz2=z23.x, zz3=z23.y;
    acc[0][0]=fmaf(zz0,w.x,acc[0][0]); acc[0][1]=fmaf(zz0,w.y,acc[0][1]); acc[0][2]=fmaf(zz0,w.z,acc[0][2]); acc[0][3]=fmaf(zz0,w.w,acc[0][3]);
    acc[1][0]=fmaf(zz1,w.x,acc[1][0]); acc[1][1]=fmaf(zz1,w.y,acc[1][1]); acc[1][2]=fmaf(zz1,w.z,acc[1][2]); acc[1][3]=fmaf(zz1,w.w,acc[1][3]);
    acc[2][0]=fmaf(zz2,w.x,acc[2][0]); acc[2][1]=fmaf(zz2,w.y,acc[2][1]); acc[2][2]=fmaf(zz2,w.z,acc[2][2]); acc[2][3]=fmaf(zz2,w.w,acc[2][3]);
    acc[3][0]=fmaf(zz3,w.x,acc[3][0]); acc[3][1]=fmaf(zz3,w.y,acc[3][1]); acc[3][2]=fmaf(zz3,w.z,acc[3][2]); acc[3][3]=fmaf(zz3,w.w,acc[3][3]);
  }
  #pragma unroll
  for (int i = 0; i < 4; ++i) {
    int gn = base + n0 + i;
    if (gn >= n) break;
    uint2 pk;
    *reinterpret_cast<__half2*>(&pk.x) = __floats2half2_rn(acc[i][0], acc[i][1]);
    *reinterpret_cast<__half2*>(&pk.y) = __floats2half2_rn(acc[i][2], acc[i][3]);
    *reinterpret_cast<uint2*>(&h[(size_t)gn*64 + cg*2]) = pk;
  }
  float4 asv = *(const float4*)(a_s + c0);
  float4 adv = *(const float4*)(a_d + c0);
  float ps[4], pd[4];
  #pragma unroll
  for (int i = 0; i < 4; ++i) {
    ps[i] = acc[i][0]*asv.x + acc[i][1]*asv.y + acc[i][2]*asv.z + acc[i][3]*asv.w;
    pd[i] = acc[i][0]*adv.x + acc[i][1]*adv.y + acc[i][2]*adv.z + acc[i][3]*adv.w;
  }
  #pragma unroll
  for (int o = 8; o <= 32; o <<= 1) {
    #pragma unroll
    for (int i = 0; i < 4; ++i) { ps[i] += __shfl_xor(ps[i], o); pd[i] += __shfl_xor(pd[i], o); }
  }
  if (((tid & 63) & 56) == 0) {
    int head = tid >> 6;
    #pragma unroll
    for (int i = 0; i < 4; ++i) {
      int gn = base + n0 + i;
      if (gn >= n) break;
      asn[gn*HEADS + head] = ps[i];
      adn[gn*HEADS + head] = pd[i];
    }
  }
}

__global__ void gemm2(const float* __restrict__ z, const float* __restrict__ W,
                      __half2* __restrict__ h2, int n)
{
  __shared__ float zt[D1][65];
  int tid = threadIdx.x;
  int base = blockIdx.x * 64;
  for (int idx = tid; idx < 64*D1; idx += 256) {
    int node = idx >> 7, k = idx & 127;
    int gn = base + node;
    zt[k][node] = (gn < n) ? z[(size_t)gn*D1 + k] : 0.f;
  }
  __syncthreads();
  int ng = tid & 7, cg = tid >> 3;
  int n0 = ng * 8, c0 = cg * 2;
  float a0[8], a1[8];
  #pragma unroll
  for (int i = 0; i < 8; ++i) { a0[i]=0.f; a1[i]=0.f; }
  #pragma unroll 8
  for (int k = 0; k < D1; ++k) {
    float2 w = *(const float2*)(W + k*OUT_DIM + c0);
    float2 z01 = *(const float2*)&zt[k][n0];
    float2 z23 = *(const float2*)&zt[k][n0+2];
    float2 z45 = *(const float2*)&zt[k][n0+4];
    float2 z67 = *(const float2*)&zt[k][n0+6];
    a0[0]=fmaf(z01.x,w.x,a0[0]); a1[0]=fmaf(z01.x,w.y,a1[0]);
    a0[1]=fmaf(z01.y,w.x,a0[1]); a1[1]=fmaf(z01.y,w.y,a1[1]);
    a0[2]=fmaf(z23.x,w.x,a0[2]); a1[2]=fmaf(z23.x,w.y,a1[2]);
    a0[3]=fmaf(z23.y,w.x,a0[3]); a1[3]=fmaf(z23.y,w.y,a1[3]);
    a0[4]=fmaf(z45.x,w.x,a0[4]); a1[4]=fmaf(z45.x,w.y,a1[4]);
    a0[5]=fmaf(z45.y,w.x,a0[5]); a1[5]=fmaf(z45.y,w.y,a1[5]);
    a0[6]=fmaf(z67.x,w.x,a0[6]); a1[6]=fmaf(z67.x,w.y,a1[6]);
    a0[7]=fmaf(z67.y,w.x,a0[7]); a1[7]=fmaf(z67.y,w.y,a1[7]);
  }
  #pragma unroll
  for (int i = 0; i < 8; ++i) {
    int gn = base + n0 + i;
    if (gn >= n) break;
    h2[(size_t)gn*32 + cg] = __floats2half2_rn(a0[i], a1[i]);
  }
}

// ========== fused per-node softmax + gather aggregation ==========

__global__ void node_agg1(const int* __restrict__ csr, const unsigned* __restrict__ offs,
                          const float* __restrict__ as1, const float4* __restrict__ ad4,
                          const uint2* __restrict__ hp4, float4* __restrict__ z1out,
                          const float4* __restrict__ b1p, const float4* __restrict__ gp,
                          const float4* __restrict__ bp, const float4* __restrict__ mmp,
                          const float4* __restrict__ vvp,
                          const float4* __restrict__ wa_s4, const float4* __restrict__ wa_d4,
                          float* __restrict__ as2out, float* __restrict__ ad2out, int n)
{
  int lane = threadIdx.x & 63;
  int node = blockIdx.x*4 + (threadIdx.x >> 6);
  if (node >= n) return;
  unsigned beg = offs[node], end = offs[node+1];
  int head = lane >> 4, sub = lane & 15;
  int h = lane >> 5, g = lane & 31;
  int lbase = (g >> 3) * 16;
  float4 advv = ad4[node];
  float adv = head==0 ? advv.x : head==1 ? advv.y : head==2 ? advv.z : advv.w;
  float a0=0.f, a1=0.f, a2=0.f, a3=0.f, s=0.f;
  unsigned len = end - beg;
  unsigned nfull = len >> 4;
  unsigned c = beg;
  for (unsigned f = 0; f < nfull; ++f, c += 16) {
    int sj = csr[c + sub];
    float al = as1[sj*HEADS + head] + adv;
    al = al > 0.f ? al : NEG_SLOPE*al;
    float w = __expf(al);
    float t = w;
    #pragma unroll
    for (int o = 8; o >= 1; o >>= 1) t += __shfl_xor(t, o);
    s += t;
    GATH1(0) GATH1(1) GATH1(2) GATH1(3) GATH1(4) GATH1(5) GATH1(6) GATH1(7)
  }
  unsigned rem = len & 15u;
  if (rem) {
    bool valid = ((unsigned)sub < rem);
    int sj = valid ? csr[c + sub] : 0;
    float al = as1[sj*HEADS + head] + adv;
    al = al > 0.f ? al : NEG_SLOPE*al;
    float w = valid ? __expf(al) : 0.f;
    float t = w;
    #pragma unroll
    for (int o = 8; o >= 1; o >>= 1) t += __shfl_xor(t, o);
    s += t;
    int it = (int)((rem + 1) >> 1);
    if (it <= 2)      { GATH1(0) GATH1(1) }
    else if (it <= 4) { GATH1(0) GATH1(1) GATH1(2) GATH1(3) }
    else if (it <= 6) { GATH1(0) GATH1(1) GATH1(2) GATH1(3) GATH1(4) GATH1(5) }
    else              { GATH1(0) GATH1(1) GATH1(2) GATH1(3) GATH1(4) GATH1(5) GATH1(6) GATH1(7) }
  }
  a0 += __shfl_xor(a0, 32); a1 += __shfl_xor(a1, 32);
  a2 += __shfl_xor(a2, 32); a3 += __shfl_xor(a3, 32);
  float sc = __shfl(s, lbase);
  float inv = 1.f / (sc + 1e-16f);
  a0 *= inv; a1 *= inv; a2 *= inv; a3 *= inv;
  if (h == 0) {
    float4 bb = b1p[g], gg = gp[g], be = bp[g], mm = mmp[g], vv = vvp[g];
    float v0 = a0 + bb.x; v0 = (v0 - mm.x) * rsqrtf(vv.x + BN_EPS) * gg.x + be.x;
    float v1 = a1 + bb.y; v1 = (v1 - mm.y) * rsqrtf(vv.y + BN_EPS) * gg.y + be.y;
    float v2 = a2 + bb.z; v2 = (v2 - mm.z) * rsqrtf(vv.z + BN_EPS) * gg.z + be.z;
    float v3 = a3 + bb.w; v3 = (v3 - mm.w) * rsqrtf(vv.w + BN_EPS) * gg.w + be.w;
    v0 = v0 > 0.f ? v0 : expm1f(v0);
    v1 = v1 > 0.f ? v1 : expm1f(v1);
    v2 = v2 > 0.f ? v2 : expm1f(v2);
    v3 = v3 > 0.f ? v3 : expm1f(v3);
    z1out[(size_t)node*32 + g] = make_float4(v0, v1, v2, v3);
    float4 wsv = wa_s4[g], wdv = wa_d4[g];
    float ps = v0*wsv.x + v1*wsv.y + v2*wsv.z + v3*wsv.w;
    float pd = v0*wdv.x + v1*wdv.y + v2*wdv.z + v3*wdv.w;
    #pragma unroll
    for (int o = 16; o >= 1; o >>= 1) { ps += __shfl_xor(ps, o); pd += __shfl_xor(pd, o); }
    if (g == 0) { as2out[node] = ps; ad2out[node] = pd; }
  }
}

__global__ void node_agg2(const int* __restrict__ csr, const unsigned* __restrict__ offs,
                          const float* __restrict__ as2, const float* __restrict__ ad2,
                          const uint2* __restrict__ hp4,
                          const float4* __restrict__ biasp, const float4* __restrict__ gp,
                          const float4* __restrict__ bp, const float4* __restrict__ bmp,
                          const float4* __restrict__ bvp,
                          float4* __restrict__ z2out, int n)
{
  int lane = threadIdx.x & 63;
  int node = blockIdx.x*4 + (threadIdx.x >> 6);
  if (node >= n) return;
  unsigned beg = offs[node], end = offs[node+1];
  int q = lane >> 4, g = lane & 15;
  int sub = lane & 15;
  float adv = ad2[node];
  float a0=0.f, a1=0.f, a2=0.f, a3=0.f, s=0.f;
  unsigned len = end - beg;
  unsigned nfull = len >> 4;
  unsigned c = beg;
  for (unsigned f = 0; f < nfull; ++f, c += 16) {
    int sj = csr[c + sub];
    float al = as2[sj] + adv;
    al = al > 0.f ? al : NEG_SLOPE*al;
    float w = __expf(al);
    float t = w;
    #pragma unroll
    for (int o = 8; o >= 1; o >>= 1) t += __shfl_xor(t, o);
    s += t;
    GATH2(0) GATH2(1) GATH2(2) GATH2(3)
  }
  unsigned rem = len & 15u;
  if (rem) {
    bool valid = ((unsigned)sub < rem);
    int sj = valid ? csr[c + sub] : 0;
    float al = as2[sj] + adv;
    al = al > 0.f ? al : NEG_SLOPE*al;
    float w = valid ? __expf(al) : 0.f;
    float t = w;
    #pragma unroll
    for (int o = 8; o >= 1; o >>= 1) t += __shfl_xor(t, o);
    s += t;
    int it = (int)((rem + 3) >> 2);
    if (it <= 1)      { GATH2(0) }
    else if (it <= 2) { GATH2(0) GATH2(1) }
    else if (it <= 3) { GATH2(0) GATH2(1) GATH2(2) }
    else              { GATH2(0) GATH2(1) GATH2(2) GATH2(3) }
  }
  a0 += __shfl_xor(a0, 32); a1 += __shfl_xor(a1, 32);
  a2 += __shfl_xor(a2, 32); a3 += __shfl_xor(a3, 32);
  a0 += __shfl_xor(a0, 16); a1 += __shfl_xor(a1, 16);
  a2 += __shfl_xor(a2, 16); a3 += __shfl_xor(a3, 16);
  float inv = 1.f / (s + 1e-16f);
  if (q == 0) {
    float4 bb = biasp[g], gg = gp[g], be = bp[g], mm = bmp[g], vv = bvp[g];
    float v0 = a0*inv + bb.x; v0 = (v0 - mm.x) * rsqrtf(vv.x + BN_EPS) * gg.x + be.x;
    float v1 = a1*inv + bb.y; v1 = (v1 - mm.y) * rsqrtf(vv.y + BN_EPS) * gg.y + be.y;
    float v2 = a2*inv + bb.z; v2 = (v2 - mm.z) * rsqrtf(vv.z + BN_EPS) * gg.z + be.z;
    float v3 = a3*inv + bb.w; v3 = (v3 - mm.w) * rsqrtf(vv.w + BN_EPS) * gg.w + be.w;
    v0 = v0 > 0.f ? v0 : expm1f(v0);
    v1 = v1 > 0.f ? v1 : expm1f(v1);
    v2 = v2 > 0.f ? v2 : expm1f(v2);
    v3 = v3 > 0.f ? v3 : expm1f(v3);
    z2out[(size_t)node*16 + g] = make_float4(v0, v1, v2, v3);
  }
}

// ---- uv_prep: register-blocked tile GEMM ----
__global__ void uv_prep(const float* __restrict__ z2, const float* __restrict__ hW1,
                        __half2* __restrict__ u, __half2* __restrict__ vout, int n)
{
  __shared__ float zt[64][65];
  int tid = threadIdx.x;
  int base = blockIdx.x * 64;
  for (int idx = tid; idx < 64*64; idx += 256) {
    int node = idx >> 6, k = idx & 63;
    int gn = base + node;
    zt[k][node] = (gn < n) ? z2[(size_t)gn*64 + k] : 0.f;
  }
  __syncthreads();
  int ng = tid & 7, cg = tid >> 3;
  int n0 = ng * 8;
  int c0 = (cg & 15) * 4;
  const float* wbase = hW1 + (cg >= 16 ? 64*64 : 0) + c0;
  float acc[8][4];
  #pragma unroll
  for (int i = 0; i < 8; ++i) { acc[i][0]=0.f; acc[i][1]=0.f; acc[i][2]=0.f; acc[i][3]=0.f; }
  #pragma unroll 8
  for (int k = 0; k < 64; ++k) {
    float4 w = *(const float4*)(wbase + k*64);
    float2 z01 = *(const float2*)&zt[k][n0];
    float2 z23 = *(const float2*)&zt[k][n0+2];
    float2 z45 = *(const float2*)&zt[k][n0+4];
    float2 z67 = *(const float2*)&zt[k][n0+6];
    float zz0=z01.x, zz1=z01.y, zz2=z23.x, zz3=z23.y, zz4=z45.x, zz5=z45.y, zz6=z67.x, zz7=z67.y;
    acc[0][0]=fmaf(zz0,w.x,acc[0][0]); acc[0][1]=fmaf(zz0,w.y,acc[0][1]); acc[0][2]=fmaf(zz0,w.z,acc[0][2]); acc[0][3]=fmaf(zz0,w.w,acc[0][3]);
    acc[1][0]=fmaf(zz1,w.x,acc[1][0]); acc[1][1]=fmaf(zz1,w.y,acc[1][1]); acc[1][2]=fmaf(zz1,w.z,acc[1][2]); acc[1][3]=fmaf(zz1,w.w,acc[1][3]);
    acc[2][0]=fmaf(zz2,w.x,acc[2][0]); acc[2][1]=fmaf(zz2,w.y,acc[2][1]); acc[2][2]=fmaf(zz2,w.z,acc[2][2]); acc[2][3]=fmaf(zz2,w.w,acc[2][3]);
    acc[3][0]=fmaf(zz3,w.x,acc[3][0]); acc[3][1]=fmaf(zz3,w.y,acc[3][1]); acc[3][2]=fmaf(zz3,w.z,acc[3][2]); acc[3][3]=fmaf(zz3,w.w,acc[3][3]);
    acc[4][0]=fmaf(zz4,w.x,acc[4][0]); acc[4][1]=fmaf(zz4,w.y,acc[4][1]); acc[4][2]=fmaf(zz4,w.z,acc[4][2]); acc[4][3]=fmaf(zz4,w.w,acc[4][3]);
    acc[5][0]=fmaf(zz5,w.x,acc[5][0]); acc[5][1]=fmaf(zz5,w.y,acc[5][1]); acc[5][2]=fmaf(zz5,w.z,acc[5][2]); acc[5][3]=fmaf(zz5,w.w,acc[5][3]);
    acc[6][0]=fmaf(zz6,w.x,acc[6][0]); acc[6][1]=fmaf(zz6,w.y,acc[6][1]); acc[6][2]=fmaf(zz6,w.z,acc[6][2]); acc[6][3]=fmaf(zz6,w.w,acc[6][3]);
    acc[7][0]=fmaf(zz7,w.x,acc[7][0]); acc[7][1]=fmaf(zz7,w.y,acc[7][1]); acc[7][2]=fmaf(zz7,w.z,acc[7][2]); acc[7][3]=fmaf(zz7,w.w,acc[7][3]);
  }
  __half2* dst = (cg < 16) ? u : vout;
  int cq = (cg & 15) * 2;
  #pragma unroll
  for (int i = 0; i < 8; ++i) {
    int gn = base + n0 + i;
    if (gn >= n) break;
    uint2 pk;
    *reinterpret_cast<__half2*>(&pk.x) = __floats2half2_rn(acc[i][0], acc[i][1]);
    *reinterpret_cast<__half2*>(&pk.y) = __floats2half2_rn(acc[i][2], acc[i][3]);
    *reinterpret_cast<uint2*>(&dst[(size_t)gn*32 + cq]) = pk;
  }
}

// ---- pair scoring ----
__global__ void pair_score(const int* __restrict__ src, const int* __restrict__ dst,
                           const uint4* __restrict__ u4, const uint4* __restrict__ v4,
                           const float4* __restrict__ hb1, const float4* __restrict__ hW2,
                           const float* __restrict__ hb2, float* __restrict__ out, int P)
{
  int t = blockIdx.x*blockDim.x + threadIdx.x;
  int p = t >> 3, sub = t & 7;
  if (p >= P) return;
  int sp = src[p], dp = dst[p];
  uint4 ua = u4[(size_t)sp*8 + sub];
  uint4 vb = v4[(size_t)dp*8 + sub];
  float4 hbA = hb1[sub*2], hbB = hb1[sub*2+1];
  float4 w2A = hW2[sub*2], w2B = hW2[sub*2+1];
  float2 a0 = h2f2(ua.x), a1 = h2f2(ua.y), a2 = h2f2(ua.z), a3 = h2f2(ua.w);
  float2 b0 = h2f2(vb.x), b1 = h2f2(vb.y), b2 = h2f2(vb.z), b3 = h2f2(vb.w);
  float h0 = a0.x + b0.x + hbA.x; h0 = h0 > 0.f ? h0 : expm1f(h0);
  float h1 = a0.y + b0.y + hbA.y; h1 = h1 > 0.f ? h1 : expm1f(h1);
  float h2 = a1.x + b1.x + hbA.z; h2 = h2 > 0.f ? h2 : expm1f(h2);
  float h3 = a1.y + b1.y + hbA.w; h3 = h3 > 0.f ? h3 : expm1f(h3);
  float h4 = a2.x + b2.x + hbB.x; h4 = h4 > 0.f ? h4 : expm1f(h4);
  float h5 = a2.y + b2.y + hbB.y; h5 = h5 > 0.f ? h5 : expm1f(h5);
  float h6 = a3.x + b3.x + hbB.z; h6 = h6 > 0.f ? h6 : expm1f(h6);
  float h7 = a3.y + b3.y + hbB.w; h7 = h7 > 0.f ? h7 : expm1f(h7);
  float pl = h0*w2A.x + h1*w2A.y + h2*w2A.z + h3*w2A.w
           + h4*w2B.x + h5*w2B.y + h6*w2B.z + h7*w2B.w;
  pl += __shfl_xor(pl, 1);
  pl += __shfl_xor(pl, 2);
  pl += __shfl_xor(pl, 4);
  if (sub == 0) out[p] = 1.f / (1.f + __expf(-(pl + hb2[0])));
}

extern "C" void kernel_launch(void* const* d_in, const int* in_sizes, int n_in,
                              void* d_out, int out_size, void* d_ws, size_t ws_size,
                              hipStream_t stream)
{
  const float* x    = (const float*)d_in[0];
  const int*   ei   = (const int*)d_in[1];
  const int*   src  = (const int*)d_in[2];
  const int*   dst  = (const int*)d_in[3];
  const float* W1   = (const float*)d_in[4];
  const float* a1s  = (const float*)d_in[5];
  const float* a1d  = (const float*)d_in[6];
  const float* b1   = (const float*)d_in[7];
  const float* bn1g = (const float*)d_in[8];
  const float* bn1b = (const float*)d_in[9];
  const float* bn1m = (const float*)d_in[10];
  const float* bn1v = (const float*)d_in[11];
  const float* W2   = (const float*)d_in[12];
  const float* a2s  = (const float*)d_in[13];
  const float* a2d  = (const float*)d_in[14];
  const float* b2   = (const float*)d_in[15];
  const float* bn2g = (const float*)d_in[16];
  const float* bn2b = (const float*)d_in[17];
  const float* bn2m = (const float*)d_in[18];
  const float* bn2v = (const float*)d_in[19];
  const float* hW1  = (const float*)d_in[20];
  const float* hb1  = (const float*)d_in[21];
  const float* hW2  = (const float*)d_in[22];
  const float* hb2  = (const float*)d_in[23];

  const int N  = in_sizes[0] / IN_DIM;
  const int E  = in_sizes[1] / 2;
  const int P  = in_sizes[2];
  const int Ep = E + N;
  const int ntiles = (N + 255) / 256;
  const int nb = (N + (1 << BSHIFT) - 1) >> BSHIFT;
  const int T  = nb * NBLK;
  const int gt = (T + 255) / 256;
  const int chunk = (Ep + NBLK - 1) / NBLK;

  // ---- workspace layout ----
  float* ws = (float*)d_ws;
  float* h1   = ws;                          // region: N*128 f32
  float* z1   = h1 + (size_t)N*D1;           // region: N*128 f32 (z1; later u/v fp16)
  float* as1  = z1 + (size_t)N*D1;           // N*4
  float* ad1  = as1 + (size_t)N*HEADS;       // N*4
  float* as2  = ad1 + (size_t)N*HEADS;       // N
  float* ad2  = as2 + N;                     // N
  unsigned* deg    = (unsigned*)(ad2 + N);   // N
  unsigned* offs   = deg + N;                // N+2
  unsigned* part   = offs + N + 2;           // ntiles
  unsigned* histg  = part + ntiles;          // T
  unsigned* scand  = histg + T;              // T
  unsigned* gpart  = scand + T;              // gt
  float* wa_s      = (float*)(gpart + gt);   // 128
  float* wa_d      = wa_s + D1;              // 128
  int* csr         = (int*)(wa_d + D1);      // Ep
  int2* pairs      = (int2*)(csr + Ep + (Ep & 1)); // Ep int2 (8B-aligned)

  __half2* h1h = (__half2*)h1;               // N*64 half2
  __half2* h2h = (__half2*)h1;               // N*32 half2 (aliases h1h; h1 dead by then)
  float*   z2  = h1 + (size_t)N*OUT_DIM;     // N*64 f32
  __half2* uh  = (__half2*)z1;               // N*32 half2 (z1 dead after gemm2)
  __half2* vh  = uh + (size_t)N*32;          // N*32 half2

  // ---- CSR build (blocked counting sort) + wa precompute ----
  hipMemsetAsync(deg, 0, (size_t)N*sizeof(unsigned), stream);
  prep_wa<<<1, 128, 0, stream>>>(W2, a2s, a2d, wa_s, wa_d);
  hist_pass<<<NBLK, 256, 0, stream>>>(ei, E, N, chunk, histg, deg);
  gsum<<<gt, 256, 0, stream>>>(histg, gpart, T);
  gscan_part<<<1, 256, 0, stream>>>(gpart, gt);
  gscan_write<<<gt, 256, 0, stream>>>(histg, gpart, scand, T);
  tile_sum<<<ntiles, 256, 0, stream>>>(deg, part, N);
  part_scan<<<1, 256, 0, stream>>>(part, offs + N, ntiles);
  tile_scan_write<<<ntiles, 256, 0, stream>>>(deg, part, offs, N);
  scatter_pass<<<NBLK, 256, 0, stream>>>(ei, E, N, chunk, scand, pairs);
  bucket_fill<<<nb, 256, 0, stream>>>(pairs, scand, offs, csr, nb, Ep);

  // ---- layer 1 ----
  gemm1<<<(N + 31)/32, 256, 0, stream>>>(x, W1, a1s, a1d, h1h, as1, ad1, N);
  node_agg1<<<(N + 3)/4, 256, 0, stream>>>(csr, offs, as1, (const float4*)ad1,
                                           (const uint2*)h1h, (float4*)z1,
                                           (const float4*)b1, (const float4*)bn1g,
                                           (const float4*)bn1b, (const float4*)bn1m,
                                           (const float4*)bn1v,
                                           (const float4*)wa_s, (const float4*)wa_d,
                                           as2, ad2, N);

  // ---- layer 2 ----
  gemm2<<<(N + 63)/64, 256, 0, stream>>>(z1, W2, h2h, N);
  node_agg2<<<(N + 3)/4, 256, 0, stream>>>(csr, offs, as2, ad2, (const uint2*)h2h,
                                           (const float4*)b2, (const float4*)bn2g,
                                           (const float4*)bn2b, (const float4*)bn2m,
                                           (const float4*)bn2v, (float4*)z2, N);
  uv_prep<<<(N + 63)/64, 256, 0, stream>>>(z2, hW1, uh, vh, N);

  // ---- pair scoring ----
  {
    long long total = (long long)P * 8;
    int blocks = (int)((total + 255) / 256);
    pair_score<<<blocks, 256, 0, stream>>>(src, dst, (const uint4*)uh, (const uint4*)vh,
                                           (const float4*)hb1, (const float4*)hW2,
                                           hb2, (float*)d_out, P);
  }
}

// Round 18
// 275.468 us; speedup vs baseline: 1.0226x; 1.0226x over previous
//
#include <hip/hip_runtime.h>
#include <hip/hip_fp16.h>
#include <cmath>

#define HEADS 4
#define HID 32
#define IN_DIM 128
#define OUT_DIM 64
#define D1 (HEADS*HID)   /* 128 */
#define NEG_SLOPE 0.2f
#define BN_EPS 1e-5f
#define BSHIFT 6         /* 64 nodes per dst-bucket */
#define NBLK 128         /* blocks for hist/scatter passes */

__device__ __forceinline__ float2 h2f2(unsigned u) {
  return __half22float2(*reinterpret_cast<const __half2*>(&u));
}

// gather bodies (straight-line; rely on w=0/sj=0 masking for invalid lanes)
#define GATH1(J2) { int k_ = (J2)*2 + h; \
  float wv_ = __shfl(w, lbase + k_); int sv_ = __shfl(sj, k_); \
  uint2 hv_ = hp4[(size_t)sv_*32 + g]; \
  float2 p0_ = h2f2(hv_.x), p1_ = h2f2(hv_.y); \
  a0 = fmaf(p0_.x, wv_, a0); a1 = fmaf(p0_.y, wv_, a1); \
  a2 = fmaf(p1_.x, wv_, a2); a3 = fmaf(p1_.y, wv_, a3); }

#define GATH2(J2) { int k_ = (J2)*4 + q; \
  float wv_ = __shfl(w, k_); int sv_ = __shfl(sj, k_); \
  uint2 hv_ = hp4[(size_t)sv_*16 + g]; \
  float2 p0_ = h2f2(hv_.x), p1_ = h2f2(hv_.y); \
  a0 = fmaf(p0_.x, wv_, a0); a1 = fmaf(p0_.y, wv_, a1); \
  a2 = fmaf(p1_.x, wv_, a2); a3 = fmaf(p1_.y, wv_, a3); }

// ================= CSR build: blocked counting sort =================

__global__ void hist_pass(const int* __restrict__ ei, int E, int n, int chunk,
                          unsigned* __restrict__ histg, unsigned* __restrict__ deg)
{
  __shared__ unsigned h[1024];
  int blk = blockIdx.x, tid = threadIdx.x;
  int nb = (n + 63) >> BSHIFT;
  for (int i = tid; i < nb; i += 256) h[i] = 0u;
  __syncthreads();
  int beg = blk*chunk, end_ = min(beg + chunk, E + n);
  for (int t = beg + tid; t < end_; t += 256) {
    int d_;
    if (t < E) { d_ = ei[E + t]; atomicAdd(&deg[d_], 1u); }
    else d_ = t - E;
    atomicAdd(&h[d_ >> BSHIFT], 1u);
  }
  __syncthreads();
  for (int i = tid; i < nb; i += 256) histg[(size_t)i*NBLK + blk] = h[i];
}

__global__ void gsum(const unsigned* __restrict__ in, unsigned* __restrict__ part, int total)
{
  __shared__ unsigned red[256];
  int tid = threadIdx.x;
  int i = blockIdx.x*256 + tid;
  red[tid] = (i < total) ? in[i] : 0u;
  __syncthreads();
  for (int o = 128; o >= 1; o >>= 1) {
    if (tid < o) red[tid] += red[tid + o];
    __syncthreads();
  }
  if (tid == 0) part[blockIdx.x] = red[0];
}

__global__ void gscan_part(unsigned* __restrict__ part, int ntiles)
{
  __shared__ unsigned sh[256];
  int tid = threadIdx.x;
  unsigned carry = 0;
  for (int base = 0; base < ntiles; base += 256) {
    int i = base + tid;
    unsigned v = (i < ntiles) ? part[i] : 0u;
    sh[tid] = v;
    __syncthreads();
    for (int o = 1; o < 256; o <<= 1) {
      unsigned t = (tid >= o) ? sh[tid - o] : 0u;
      __syncthreads();
      sh[tid] += t;
      __syncthreads();
    }
    if (i < ntiles) part[i] = carry + sh[tid] - v;
    unsigned tot = sh[255];
    __syncthreads();
    carry += tot;
  }
}

__global__ void gscan_write(const unsigned* __restrict__ in, const unsigned* __restrict__ part,
                            unsigned* __restrict__ out, int total)
{
  __shared__ unsigned sh[256];
  int tid = threadIdx.x;
  int i = blockIdx.x*256 + tid;
  unsigned v = (i < total) ? in[i] : 0u;
  sh[tid] = v;
  __syncthreads();
  for (int o = 1; o < 256; o <<= 1) {
    unsigned t = (tid >= o) ? sh[tid - o] : 0u;
    __syncthreads();
    sh[tid] += t;
    __syncthreads();
  }
  if (i < total) out[i] = part[blockIdx.x] + sh[tid] - v;
}

// node offsets derived from scand: offs[first node of bucket b] == scand[b*NBLK];
// within bucket, 64-wide wave scan of deg+1. Replaces 3 scan kernels.
__global__ void bucket_offs(const unsigned* __restrict__ deg, const unsigned* __restrict__ scand,
                            unsigned* __restrict__ offs, int n, int nb)
{
  int wave = threadIdx.x >> 6, lane = threadIdx.x & 63;
  int b = blockIdx.x*4 + wave;
  if (b >= nb) return;
  int node = b*64 + lane;
  unsigned base = scand[(size_t)b*NBLK];
  unsigned v = (node < n) ? deg[node] + 1u : 0u;
  unsigned incl = v;
  #pragma unroll
  for (int o = 1; o < 64; o <<= 1) {
    unsigned t = __shfl_up(incl, o);
    if (lane >= o) incl += t;
  }
  if (node < n) offs[node] = base + incl - v;
  if (node + 1 == n) offs[n] = base + incl;
}

__global__ void scatter_pass(const int* __restrict__ ei, int E, int n, int chunk,
                             const unsigned* __restrict__ scanned, int2* __restrict__ pairs)
{
  __shared__ unsigned basel[1024];
  __shared__ unsigned lcur[1024];
  int blk = blockIdx.x, tid = threadIdx.x;
  int nb = (n + 63) >> BSHIFT;
  for (int i = tid; i < nb; i += 256) {
    basel[i] = scanned[(size_t)i*NBLK + blk];
    lcur[i] = 0u;
  }
  __syncthreads();
  int beg = blk*chunk, end_ = min(beg + chunk, E + n);
  for (int t = beg + tid; t < end_; t += 256) {
    int s_, d_;
    if (t < E) { s_ = ei[t]; d_ = ei[E + t]; } else { s_ = d_ = t - E; }
    int b = d_ >> BSHIFT;
    unsigned r = atomicAdd(&lcur[b], 1u);
    pairs[basel[b] + r] = make_int2(s_, d_);
  }
}

__global__ void bucket_fill(const int2* __restrict__ pairs, const unsigned* __restrict__ scanned,
                            const unsigned* __restrict__ offs, int* __restrict__ csr,
                            int nb, int total)
{
  __shared__ unsigned curs[64];
  int b = blockIdx.x, tid = threadIdx.x;
  if (tid < 64) curs[tid] = 0u;
  __syncthreads();
  unsigned pb = scanned[(size_t)b*NBLK];
  unsigned pe = (b + 1 < nb) ? scanned[(size_t)(b+1)*NBLK] : (unsigned)total;
  for (unsigned i = pb + tid; i < pe; i += blockDim.x) {
    int2 pr = pairs[i];
    unsigned rank = atomicAdd(&curs[pr.y & 63], 1u);
    csr[offs[pr.y] + rank] = pr.x;
  }
}

__global__ void prep_wa(const float* __restrict__ W2, const float* __restrict__ a2s,
                        const float* __restrict__ a2d,
                        float* __restrict__ wa_s, float* __restrict__ wa_d)
{
  int k = threadIdx.x;
  float s = 0.f, d = 0.f;
  for (int j = 0; j < OUT_DIM; ++j) {
    float w = W2[k*OUT_DIM + j];
    s = fmaf(w, a2s[j], s);
    d = fmaf(w, a2d[j], d);
  }
  wa_s[k] = s; wa_d[k] = d;
}

// ================= dense GEMMs: register-blocked tiles =================

__global__ void gemm1(const float* __restrict__ x, const float* __restrict__ W,
                      const float* __restrict__ a_s, const float* __restrict__ a_d,
                      __half2* __restrict__ h, float* __restrict__ asn,
                      float* __restrict__ adn, int n)
{
  __shared__ float xt[IN_DIM][33];
  int tid = threadIdx.x;
  int base = blockIdx.x * 32;
  for (int idx = tid; idx < 32*IN_DIM; idx += 256) {
    int node = idx >> 7, k = idx & 127;
    int gn = base + node;
    xt[k][node] = (gn < n) ? x[(size_t)gn*IN_DIM + k] : 0.f;
  }
  __syncthreads();
  int ng = tid & 7, cg = tid >> 3;
  int n0 = ng * 4, c0 = cg * 4;
  float acc[4][4];
  #pragma unroll
  for (int i = 0; i < 4; ++i) { acc[i][0]=0.f; acc[i][1]=0.f; acc[i][2]=0.f; acc[i][3]=0.f; }
  #pragma unroll 8
  for (int k = 0; k < IN_DIM; ++k) {
    float4 w = *(const float4*)(W + k*D1 + c0);
    float2 z01 = *(const float2*)&xt[k][n0];
    float2 z23 = *(const float2*)&xt[k][n0+2];
    float zz0=z01.x, zz1=z01.y, zz2=z23.x, zz3=z23.y;
    acc[0][0]=fmaf(zz0,w.x,acc[0][0]); acc[0][1]=fmaf(zz0,w.y,acc[0][1]); acc[0][2]=fmaf(zz0,w.z,acc[0][2]); acc[0][3]=fmaf(zz0,w.w,acc[0][3]);
    acc[1][0]=fmaf(zz1,w.x,acc[1][0]); acc[1][1]=fmaf(zz1,w.y,acc[1][1]); acc[1][2]=fmaf(zz1,w.z,acc[1][2]); acc[1][3]=fmaf(zz1,w.w,acc[1][3]);
    acc[2][0]=fmaf(zz2,w.x,acc[2][0]); acc[2][1]=fmaf(zz2,w.y,acc[2][1]); acc[2][2]=fmaf(zz2,w.z,acc[2][2]); acc[2][3]=fmaf(zz2,w.w,acc[2][3]);
    acc[3][0]=fmaf(zz3,w.x,acc[3][0]); acc[3][1]=fmaf(zz3,w.y,acc[3][1]); acc[3][2]=fmaf(zz3,w.z,acc[3][2]); acc[3][3]=fmaf(zz3,w.w,acc[3][3]);
  }
  #pragma unroll
  for (int i = 0; i < 4; ++i) {
    int gn = base + n0 + i;
    if (gn >= n) break;
    uint2 pk;
    *reinterpret_cast<__half2*>(&pk.x) = __floats2half2_rn(acc[i][0], acc[i][1]);
    *reinterpret_cast<__half2*>(&pk.y) = __floats2half2_rn(acc[i][2], acc[i][3]);
    *reinterpret_cast<uint2*>(&h[(size_t)gn*64 + cg*2]) = pk;
  }
  float4 asv = *(const float4*)(a_s + c0);
  float4 adv = *(const float4*)(a_d + c0);
  float ps[4], pd[4];
  #pragma unroll
  for (int i = 0; i < 4; ++i) {
    ps[i] = acc[i][0]*asv.x + acc[i][1]*asv.y + acc[i][2]*asv.z + acc[i][3]*asv.w;
    pd[i] = acc[i][0]*adv.x + acc[i][1]*adv.y + acc[i][2]*adv.z + acc[i][3]*adv.w;
  }
  #pragma unroll
  for (int o = 8; o <= 32; o <<= 1) {
    #pragma unroll
    for (int i = 0; i < 4; ++i) { ps[i] += __shfl_xor(ps[i], o); pd[i] += __shfl_xor(pd[i], o); }
  }
  if (((tid & 63) & 56) == 0) {
    int head = tid >> 6;
    #pragma unroll
    for (int i = 0; i < 4; ++i) {
      int gn = base + n0 + i;
      if (gn >= n) break;
      asn[gn*HEADS + head] = ps[i];
      adn[gn*HEADS + head] = pd[i];
    }
  }
}

__global__ void gemm2(const float* __restrict__ z, const float* __restrict__ W,
                      __half2* __restrict__ h2, int n)
{
  __shared__ float zt[D1][65];
  int tid = threadIdx.x;
  int base = blockIdx.x * 64;
  for (int idx = tid; idx < 64*D1; idx += 256) {
    int node = idx >> 7, k = idx & 127;
    int gn = base + node;
    zt[k][node] = (gn < n) ? z[(size_t)gn*D1 + k] : 0.f;
  }
  __syncthreads();
  int ng = tid & 7, cg = tid >> 3;
  int n0 = ng * 8, c0 = cg * 2;
  float a0[8], a1[8];
  #pragma unroll
  for (int i = 0; i < 8; ++i) { a0[i]=0.f; a1[i]=0.f; }
  #pragma unroll 8
  for (int k = 0; k < D1; ++k) {
    float2 w = *(const float2*)(W + k*OUT_DIM + c0);
    float2 z01 = *(const float2*)&zt[k][n0];
    float2 z23 = *(const float2*)&zt[k][n0+2];
    float2 z45 = *(const float2*)&zt[k][n0+4];
    float2 z67 = *(const float2*)&zt[k][n0+6];
    a0[0]=fmaf(z01.x,w.x,a0[0]); a1[0]=fmaf(z01.x,w.y,a1[0]);
    a0[1]=fmaf(z01.y,w.x,a0[1]); a1[1]=fmaf(z01.y,w.y,a1[1]);
    a0[2]=fmaf(z23.x,w.x,a0[2]); a1[2]=fmaf(z23.x,w.y,a1[2]);
    a0[3]=fmaf(z23.y,w.x,a0[3]); a1[3]=fmaf(z23.y,w.y,a1[3]);
    a0[4]=fmaf(z45.x,w.x,a0[4]); a1[4]=fmaf(z45.x,w.y,a1[4]);
    a0[5]=fmaf(z45.y,w.x,a0[5]); a1[5]=fmaf(z45.y,w.y,a1[5]);
    a0[6]=fmaf(z67.x,w.x,a0[6]); a1[6]=fmaf(z67.x,w.y,a1[6]);
    a0[7]=fmaf(z67.y,w.x,a0[7]); a1[7]=fmaf(z67.y,w.y,a1[7]);
  }
  #pragma unroll
  for (int i = 0; i < 8; ++i) {
    int gn = base + n0 + i;
    if (gn >= n) break;
    h2[(size_t)gn*32 + cg] = __floats2half2_rn(a0[i], a1[i]);
  }
}

// ========== fused per-node softmax + gather aggregation ==========
// Softmax sum is HOISTED: per-lane partial s += w, ONE 16-lane reduce at the end
// (valid because normalization is a post-hoc divide; no max-subtraction).

__global__ void node_agg1(const int* __restrict__ csr, const unsigned* __restrict__ offs,
                          const float* __restrict__ as1, const float4* __restrict__ ad4,
                          const uint2* __restrict__ hp4, float4* __restrict__ z1out,
                          const float4* __restrict__ b1p, const float4* __restrict__ gp,
                          const float4* __restrict__ bp, const float4* __restrict__ mmp,
                          const float4* __restrict__ vvp,
                          const float4* __restrict__ wa_s4, const float4* __restrict__ wa_d4,
                          float* __restrict__ as2out, float* __restrict__ ad2out, int n)
{
  int lane = threadIdx.x & 63;
  int node = blockIdx.x*4 + (threadIdx.x >> 6);
  if (node >= n) return;
  unsigned beg = offs[node], end = offs[node+1];
  int head = lane >> 4, sub = lane & 15;
  int h = lane >> 5, g = lane & 31;
  int lbase = (g >> 3) * 16;
  float4 advv = ad4[node];
  float adv = head==0 ? advv.x : head==1 ? advv.y : head==2 ? advv.z : advv.w;
  float a0=0.f, a1=0.f, a2=0.f, a3=0.f, s=0.f;
  unsigned len = end - beg;
  unsigned nfull = len >> 4;
  unsigned c = beg;
  for (unsigned f = 0; f < nfull; ++f, c += 16) {
    int sj = csr[c + sub];
    float al = as1[sj*HEADS + head] + adv;
    al = al > 0.f ? al : NEG_SLOPE*al;
    float w = __expf(al);
    s += w;                              // per-lane partial; reduced once at end
    GATH1(0) GATH1(1) GATH1(2) GATH1(3) GATH1(4) GATH1(5) GATH1(6) GATH1(7)
  }
  unsigned rem = len & 15u;
  if (rem) {
    bool valid = ((unsigned)sub < rem);
    int sj = valid ? csr[c + sub] : 0;
    float al = as1[sj*HEADS + head] + adv;
    al = al > 0.f ? al : NEG_SLOPE*al;
    float w = valid ? __expf(al) : 0.f;
    s += w;
    int it = (int)((rem + 1) >> 1);
    if (it <= 2)      { GATH1(0) GATH1(1) }
    else if (it <= 4) { GATH1(0) GATH1(1) GATH1(2) GATH1(3) }
    else if (it <= 6) { GATH1(0) GATH1(1) GATH1(2) GATH1(3) GATH1(4) GATH1(5) }
    else              { GATH1(0) GATH1(1) GATH1(2) GATH1(3) GATH1(4) GATH1(5) GATH1(6) GATH1(7) }
  }
  // one softmax-sum reduce (within each head's 16-lane group)
  #pragma unroll
  for (int o = 8; o >= 1; o >>= 1) s += __shfl_xor(s, o);
  a0 += __shfl_xor(a0, 32); a1 += __shfl_xor(a1, 32);
  a2 += __shfl_xor(a2, 32); a3 += __shfl_xor(a3, 32);
  float sc = __shfl(s, lbase);
  float inv = 1.f / (sc + 1e-16f);
  a0 *= inv; a1 *= inv; a2 *= inv; a3 *= inv;
  if (h == 0) {
    float4 bb = b1p[g], gg = gp[g], be = bp[g], mm = mmp[g], vv = vvp[g];
    float v0 = a0 + bb.x; v0 = (v0 - mm.x) * rsqrtf(vv.x + BN_EPS) * gg.x + be.x;
    float v1 = a1 + bb.y; v1 = (v1 - mm.y) * rsqrtf(vv.y + BN_EPS) * gg.y + be.y;
    float v2 = a2 + bb.z; v2 = (v2 - mm.z) * rsqrtf(vv.z + BN_EPS) * gg.z + be.z;
    float v3 = a3 + bb.w; v3 = (v3 - mm.w) * rsqrtf(vv.w + BN_EPS) * gg.w + be.w;
    v0 = v0 > 0.f ? v0 : expm1f(v0);
    v1 = v1 > 0.f ? v1 : expm1f(v1);
    v2 = v2 > 0.f ? v2 : expm1f(v2);
    v3 = v3 > 0.f ? v3 : expm1f(v3);
    z1out[(size_t)node*32 + g] = make_float4(v0, v1, v2, v3);
    float4 wsv = wa_s4[g], wdv = wa_d4[g];
    float ps = v0*wsv.x + v1*wsv.y + v2*wsv.z + v3*wsv.w;
    float pd = v0*wdv.x + v1*wdv.y + v2*wdv.z + v3*wdv.w;
    #pragma unroll
    for (int o = 16; o >= 1; o >>= 1) { ps += __shfl_xor(ps, o); pd += __shfl_xor(pd, o); }
    if (g == 0) { as2out[node] = ps; ad2out[node] = pd; }
  }
}

__global__ void node_agg2(const int* __restrict__ csr, const unsigned* __restrict__ offs,
                          const float* __restrict__ as2, const float* __restrict__ ad2,
                          const uint2* __restrict__ hp4,
                          const float4* __restrict__ biasp, const float4* __restrict__ gp,
                          const float4* __restrict__ bp, const float4* __restrict__ bmp,
                          const float4* __restrict__ bvp,
                          float4* __restrict__ z2out, int n)
{
  int lane = threadIdx.x & 63;
  int node = blockIdx.x*4 + (threadIdx.x >> 6);
  if (node >= n) return;
  unsigned beg = offs[node], end = offs[node+1];
  int q = lane >> 4, g = lane & 15;
  int sub = lane & 15;
  float adv = ad2[node];
  float a0=0.f, a1=0.f, a2=0.f, a3=0.f, s=0.f;
  unsigned len = end - beg;
  unsigned nfull = len >> 4;
  unsigned c = beg;
  for (unsigned f = 0; f < nfull; ++f, c += 16) {
    int sj = csr[c + sub];
    float al = as2[sj] + adv;
    al = al > 0.f ? al : NEG_SLOPE*al;
    float w = __expf(al);
    s += w;
    GATH2(0) GATH2(1) GATH2(2) GATH2(3)
  }
  unsigned rem = len & 15u;
  if (rem) {
    bool valid = ((unsigned)sub < rem);
    int sj = valid ? csr[c + sub] : 0;
    float al = as2[sj] + adv;
    al = al > 0.f ? al : NEG_SLOPE*al;
    float w = valid ? __expf(al) : 0.f;
    s += w;
    int it = (int)((rem + 3) >> 2);
    if (it <= 1)      { GATH2(0) }
    else if (it <= 2) { GATH2(0) GATH2(1) }
    else if (it <= 3) { GATH2(0) GATH2(1) GATH2(2) }
    else              { GATH2(0) GATH2(1) GATH2(2) GATH2(3) }
  }
  // one softmax-sum reduce (quarters hold identical partials -> 16-lane reduce)
  #pragma unroll
  for (int o = 8; o >= 1; o >>= 1) s += __shfl_xor(s, o);
  a0 += __shfl_xor(a0, 32); a1 += __shfl_xor(a1, 32);
  a2 += __shfl_xor(a2, 32); a3 += __shfl_xor(a3, 32);
  a0 += __shfl_xor(a0, 16); a1 += __shfl_xor(a1, 16);
  a2 += __shfl_xor(a2, 16); a3 += __shfl_xor(a3, 16);
  float inv = 1.f / (s + 1e-16f);
  if (q == 0) {
    float4 bb = biasp[g], gg = gp[g], be = bp[g], mm = bmp[g], vv = bvp[g];
    float v0 = a0*inv + bb.x; v0 = (v0 - mm.x) * rsqrtf(vv.x + BN_EPS) * gg.x + be.x;
    float v1 = a1*inv + bb.y; v1 = (v1 - mm.y) * rsqrtf(vv.y + BN_EPS) * gg.y + be.y;
    float v2 = a2*inv + bb.z; v2 = (v2 - mm.z) * rsqrtf(vv.z + BN_EPS) * gg.z + be.z;
    float v3 = a3*inv + bb.w; v3 = (v3 - mm.w) * rsqrtf(vv.w + BN_EPS) * gg.w + be.w;
    v0 = v0 > 0.f ? v0 : expm1f(v0);
    v1 = v1 > 0.f ? v1 : expm1f(v1);
    v2 = v2 > 0.f ? v2 : expm1f(v2);
    v3 = v3 > 0.f ? v3 : expm1f(v3);
    z2out[(size_t)node*16 + g] = make_float4(v0, v1, v2, v3);
  }
}

// ---- uv_prep: register-blocked tile GEMM ----
__global__ void uv_prep(const float* __restrict__ z2, const float* __restrict__ hW1,
                        __half2* __restrict__ u, __half2* __restrict__ vout, int n)
{
  __shared__ float zt[64][65];
  int tid = threadIdx.x;
  int base = blockIdx.x * 64;
  for (int idx = tid; idx < 64*64; idx += 256) {
    int node = idx >> 6, k = idx & 63;
    int gn = base + node;
    zt[k][node] = (gn < n) ? z2[(size_t)gn*64 + k] : 0.f;
  }
  __syncthreads();
  int ng = tid & 7, cg = tid >> 3;
  int n0 = ng * 8;
  int c0 = (cg & 15) * 4;
  const float* wbase = hW1 + (cg >= 16 ? 64*64 : 0) + c0;
  float acc[8][4];
  #pragma unroll
  for (int i = 0; i < 8; ++i) { acc[i][0]=0.f; acc[i][1]=0.f; acc[i][2]=0.f; acc[i][3]=0.f; }
  #pragma unroll 8
  for (int k = 0; k < 64; ++k) {
    float4 w = *(const float4*)(wbase + k*64);
    float2 z01 = *(const float2*)&zt[k][n0];
    float2 z23 = *(const float2*)&zt[k][n0+2];
    float2 z45 = *(const float2*)&zt[k][n0+4];
    float2 z67 = *(const float2*)&zt[k][n0+6];
    float zz0=z01.x, zz1=z01.y, zz2=z23.x, zz3=z23.y, zz4=z45.x, zz5=z45.y, zz6=z67.x, zz7=z67.y;
    acc[0][0]=fmaf(zz0,w.x,acc[0][0]); acc[0][1]=fmaf(zz0,w.y,acc[0][1]); acc[0][2]=fmaf(zz0,w.z,acc[0][2]); acc[0][3]=fmaf(zz0,w.w,acc[0][3]);
    acc[1][0]=fmaf(zz1,w.x,acc[1][0]); acc[1][1]=fmaf(zz1,w.y,acc[1][1]); acc[1][2]=fmaf(zz1,w.z,acc[1][2]); acc[1][3]=fmaf(zz1,w.w,acc[1][3]);
    acc[2][0]=fmaf(zz2,w.x,acc[2][0]); acc[2][1]=fmaf(zz2,w.y,acc[2][1]); acc[2][2]=fmaf(zz2,w.z,acc[2][2]); acc[2][3]=fmaf(zz2,w.w,acc[2][3]);
    acc[3][0]=fmaf(zz3,w.x,acc[3][0]); acc[3][1]=fmaf(zz3,w.y,acc[3][1]); acc[3][2]=fmaf(zz3,w.z,acc[3][2]); acc[3][3]=fmaf(zz3,w.w,acc[3][3]);
    acc[4][0]=fmaf(zz4,w.x,acc[4][0]); acc[4][1]=fmaf(zz4,w.y,acc[4][1]); acc[4][2]=fmaf(zz4,w.z,acc[4][2]); acc[4][3]=fmaf(zz4,w.w,acc[4][3]);
    acc[5][0]=fmaf(zz5,w.x,acc[5][0]); acc[5][1]=fmaf(zz5,w.y,acc[5][1]); acc[5][2]=fmaf(zz5,w.z,acc[5][2]); acc[5][3]=fmaf(zz5,w.w,acc[5][3]);
    acc[6][0]=fmaf(zz6,w.x,acc[6][0]); acc[6][1]=fmaf(zz6,w.y,acc[6][1]); acc[6][2]=fmaf(zz6,w.z,acc[6][2]); acc[6][3]=fmaf(zz6,w.w,acc[6][3]);
    acc[7][0]=fmaf(zz7,w.x,acc[7][0]); acc[7][1]=fmaf(zz7,w.y,acc[7][1]); acc[7][2]=fmaf(zz7,w.z,acc[7][2]); acc[7][3]=fmaf(zz7,w.w,acc[7][3]);
  }
  __half2* dst = (cg < 16) ? u : vout;
  int cq = (cg & 15) * 2;
  #pragma unroll
  for (int i = 0; i < 8; ++i) {
    int gn = base + n0 + i;
    if (gn >= n) break;
    uint2 pk;
    *reinterpret_cast<__half2*>(&pk.x) = __floats2half2_rn(acc[i][0], acc[i][1]);
    *reinterpret_cast<__half2*>(&pk.y) = __floats2half2_rn(acc[i][2], acc[i][3]);
    *reinterpret_cast<uint2*>(&dst[(size_t)gn*32 + cq]) = pk;
  }
}

// ---- pair scoring ----
__global__ void pair_score(const int* __restrict__ src, const int* __restrict__ dst,
                           const uint4* __restrict__ u4, const uint4* __restrict__ v4,
                           const float4* __restrict__ hb1, const float4* __restrict__ hW2,
                           const float* __restrict__ hb2, float* __restrict__ out, int P)
{
  int t = blockIdx.x*blockDim.x + threadIdx.x;
  int p = t >> 3, sub = t & 7;
  if (p >= P) return;
  int sp = src[p], dp = dst[p];
  uint4 ua = u4[(size_t)sp*8 + sub];
  uint4 vb = v4[(size_t)dp*8 + sub];
  float4 hbA = hb1[sub*2], hbB = hb1[sub*2+1];
  float4 w2A = hW2[sub*2], w2B = hW2[sub*2+1];
  float2 a0 = h2f2(ua.x), a1 = h2f2(ua.y), a2 = h2f2(ua.z), a3 = h2f2(ua.w);
  float2 b0 = h2f2(vb.x), b1 = h2f2(vb.y), b2 = h2f2(vb.z), b3 = h2f2(vb.w);
  float h0 = a0.x + b0.x + hbA.x; h0 = h0 > 0.f ? h0 : expm1f(h0);
  float h1 = a0.y + b0.y + hbA.y; h1 = h1 > 0.f ? h1 : expm1f(h1);
  float h2 = a1.x + b1.x + hbA.z; h2 = h2 > 0.f ? h2 : expm1f(h2);
  float h3 = a1.y + b1.y + hbA.w; h3 = h3 > 0.f ? h3 : expm1f(h3);
  float h4 = a2.x + b2.x + hbB.x; h4 = h4 > 0.f ? h4 : expm1f(h4);
  float h5 = a2.y + b2.y + hbB.y; h5 = h5 > 0.f ? h5 : expm1f(h5);
  float h6 = a3.x + b3.x + hbB.z; h6 = h6 > 0.f ? h6 : expm1f(h6);
  float h7 = a3.y + b3.y + hbB.w; h7 = h7 > 0.f ? h7 : expm1f(h7);
  float pl = h0*w2A.x + h1*w2A.y + h2*w2A.z + h3*w2A.w
           + h4*w2B.x + h5*w2B.y + h6*w2B.z + h7*w2B.w;
  pl += __shfl_xor(pl, 1);
  pl += __shfl_xor(pl, 2);
  pl += __shfl_xor(pl, 4);
  if (sub == 0) out[p] = 1.f / (1.f + __expf(-(pl + hb2[0])));
}

extern "C" void kernel_launch(void* const* d_in, const int* in_sizes, int n_in,
                              void* d_out, int out_size, void* d_ws, size_t ws_size,
                              hipStream_t stream)
{
  const float* x    = (const float*)d_in[0];
  const int*   ei   = (const int*)d_in[1];
  const int*   src  = (const int*)d_in[2];
  const int*   dst  = (const int*)d_in[3];
  const float* W1   = (const float*)d_in[4];
  const float* a1s  = (const float*)d_in[5];
  const float* a1d  = (const float*)d_in[6];
  const float* b1   = (const float*)d_in[7];
  const float* bn1g = (const float*)d_in[8];
  const float* bn1b = (const float*)d_in[9];
  const float* bn1m = (const float*)d_in[10];
  const float* bn1v = (const float*)d_in[11];
  const float* W2   = (const float*)d_in[12];
  const float* a2s  = (const float*)d_in[13];
  const float* a2d  = (const float*)d_in[14];
  const float* b2   = (const float*)d_in[15];
  const float* bn2g = (const float*)d_in[16];
  const float* bn2b = (const float*)d_in[17];
  const float* bn2m = (const float*)d_in[18];
  const float* bn2v = (const float*)d_in[19];
  const float* hW1  = (const float*)d_in[20];
  const float* hb1  = (const float*)d_in[21];
  const float* hW2  = (const float*)d_in[22];
  const float* hb2  = (const float*)d_in[23];

  const int N  = in_sizes[0] / IN_DIM;
  const int E  = in_sizes[1] / 2;
  const int P  = in_sizes[2];
  const int Ep = E + N;
  const int nb = (N + (1 << BSHIFT) - 1) >> BSHIFT;
  const int T  = nb * NBLK;
  const int gt = (T + 255) / 256;
  const int chunk = (Ep + NBLK - 1) / NBLK;

  // ---- workspace layout ----
  float* ws = (float*)d_ws;
  float* h1   = ws;                          // region: N*128 f32
  float* z1   = h1 + (size_t)N*D1;           // region: N*128 f32 (z1; later u/v fp16)
  float* as1  = z1 + (size_t)N*D1;           // N*4
  float* ad1  = as1 + (size_t)N*HEADS;       // N*4
  float* as2  = ad1 + (size_t)N*HEADS;       // N
  float* ad2  = as2 + N;                     // N
  unsigned* deg    = (unsigned*)(ad2 + N);   // N
  unsigned* offs   = deg + N;                // N+2
  unsigned* histg  = offs + N + 2;           // T
  unsigned* scand  = histg + T;              // T
  unsigned* gpart  = scand + T;              // gt
  float* wa_s      = (float*)(gpart + gt);   // 128
  float* wa_d      = wa_s + D1;              // 128
  int* csr         = (int*)(wa_d + D1);      // Ep
  int2* pairs      = (int2*)(csr + Ep + (Ep & 1)); // Ep int2 (8B-aligned)

  __half2* h1h = (__half2*)h1;               // N*64 half2
  __half2* h2h = (__half2*)h1;               // N*32 half2 (aliases h1h; h1 dead by then)
  float*   z2  = h1 + (size_t)N*OUT_DIM;     // N*64 f32
  __half2* uh  = (__half2*)z1;               // N*32 half2 (z1 dead after gemm2)
  __half2* vh  = uh + (size_t)N*32;          // N*32 half2

  // ---- CSR build (blocked counting sort) + wa precompute ----
  hipMemsetAsync(deg, 0, (size_t)N*sizeof(unsigned), stream);
  prep_wa<<<1, 128, 0, stream>>>(W2, a2s, a2d, wa_s, wa_d);
  hist_pass<<<NBLK, 256, 0, stream>>>(ei, E, N, chunk, histg, deg);
  gsum<<<gt, 256, 0, stream>>>(histg, gpart, T);
  gscan_part<<<1, 256, 0, stream>>>(gpart, gt);
  gscan_write<<<gt, 256, 0, stream>>>(histg, gpart, scand, T);
  bucket_offs<<<(nb + 3)/4, 256, 0, stream>>>(deg, scand, offs, N, nb);
  scatter_pass<<<NBLK, 256, 0, stream>>>(ei, E, N, chunk, scand, pairs);
  bucket_fill<<<nb, 256, 0, stream>>>(pairs, scand, offs, csr, nb, Ep);

  // ---- layer 1 ----
  gemm1<<<(N + 31)/32, 256, 0, stream>>>(x, W1, a1s, a1d, h1h, as1, ad1, N);
  node_agg1<<<(N + 3)/4, 256, 0, stream>>>(csr, offs, as1, (const float4*)ad1,
                                           (const uint2*)h1h, (float4*)z1,
                                           (const float4*)b1, (const float4*)bn1g,
                                           (const float4*)bn1b, (const float4*)bn1m,
                                           (const float4*)bn1v,
                                           (const float4*)wa_s, (const float4*)wa_d,
                                           as2, ad2, N);

  // ---- layer 2 ----
  gemm2<<<(N + 63)/64, 256, 0, stream>>>(z1, W2, h2h, N);
  node_agg2<<<(N + 3)/4, 256, 0, stream>>>(csr, offs, as2, ad2, (const uint2*)h2h,
                                           (const float4*)b2, (const float4*)bn2g,
                                           (const float4*)bn2b, (const float4*)bn2m,
                                           (const float4*)bn2v, (float4*)z2, N);
  uv_prep<<<(N + 63)/64, 256, 0, stream>>>(z2, hW1, uh, vh, N);

  // ---- pair scoring ----
  {
    long long total = (long long)P * 8;
    int blocks = (int)((total + 255) / 256);
    pair_score<<<blocks, 256, 0, stream>>>(src, dst, (const uint4*)uh, (const uint4*)vh,
                                           (const float4*)hb1, (const float4*)hW2,
                                           hb2, (float*)d_out, P);
  }
}